// Round 8
// baseline (33009.818 us; speedup 1.0000x reference)
//
#include <hip/hip_runtime.h>

// RNNModel: B=64, T=512, D_IN=256, H=1024, L=3, D_OUT=128 (all fp32)
// R8: fully-fused 3-layer cooperative wavefront pipeline. Wall step g computes
//     L0@g, L1@g-1, L2@g-2 (514 steps vs 1536). Per WG [16b x 16n]: 5 weight
//     slices f32 in regs (160 VGPR), h states f16 in LDS (96KB, state-rounding
//     only -- R7 taught f16 WEIGHTS are fatal, f16 state is cheap). Matvec via
//     fmaf((float)h16, w32, acc) -> v_fma_mix_f32. R6 flag/poll/sc-load sync.
#define NB   64
#define NT   512
#define DIN  256
#define NH   1024
#define DOUT 128
#define NSTEP (NT + 2)   // 514 wall steps

typedef float f4 __attribute__((ext_vector_type(4)));
typedef unsigned short bfr;   // raw bf16 storage

__device__ __forceinline__ float b2f(bfr u) {
    union { unsigned u; float f; } v; v.u = ((unsigned)u) << 16; return v.f;
}
__device__ __forceinline__ bfr f2b(float f) {   // round-to-nearest-even
    union { float f; unsigned u; } v; v.f = f;
    unsigned r = v.u + 0x7FFFu + ((v.u >> 16) & 1u);
    return (bfr)(r >> 16);
}
__device__ __forceinline__ unsigned packh(float a, float b) {   // 2 f32 -> f16x2 RNE
    union { ushort s; _Float16 f; } x, y;
    x.f = (_Float16)a; y.f = (_Float16)b;
    return (unsigned)x.s | ((unsigned)y.s << 16);
}
__device__ __forceinline__ float h2f(ushort u) {
    union { ushort s; _Float16 f; } x; x.s = u; return (float)x.f;
}

template <typename T> __device__ __forceinline__ f4 load4(const T* p);
template <> __device__ __forceinline__ f4 load4<float>(const float* p) { return *(const f4*)p; }
template <> __device__ __forceinline__ f4 load4<bfr>(const bfr* p) {
    ushort4 u = *(const ushort4*)p;
    f4 r; r[0] = b2f(u.x); r[1] = b2f(u.y); r[2] = b2f(u.z); r[3] = b2f(u.w); return r;
}
template <typename T> __device__ __forceinline__ void store1(T* p, float v);
template <> __device__ __forceinline__ void store1<float>(float* p, float v) { *p = v; }
template <> __device__ __forceinline__ void store1<bfr>(bfr* p, float v) { *p = f2b(v); }
template <typename T> __device__ __forceinline__ float load1(const T* p);
template <> __device__ __forceinline__ float load1<float>(const float* p) { return *p; }
template <> __device__ __forceinline__ float load1<bfr>(const bfr* p) { return b2f(*p); }

// ===================== layer-0 input projection GEMM (proven) ===================
template <int K, typename TA, typename TO>
__global__ __launch_bounds__(256)
void proj_kernel(const TA* __restrict__ A, const float* __restrict__ W,
                 const float* __restrict__ bih, const float* __restrict__ bhh,
                 TO* __restrict__ out)
{
    __shared__ float As[16][68];
    __shared__ float Ws[16][68];
    const int tid = threadIdx.x;
    const int m0 = (blockIdx.x >> 4) << 6;
    const int n0 = (blockIdx.x & 15) << 6;
    const int tm = tid & 15, tn = tid >> 4;
    const int lr = tid >> 2, lc = tid & 3;

    float acc[4][4] = {};
    for (int k0 = 0; k0 < K; k0 += 16) {
        f4 av = load4<TA>(&A[(long)(m0 + lr) * K + k0 + lc * 4]);
        f4 wv = *(const f4*)&W[(n0 + lr) * K + k0 + lc * 4];
        __syncthreads();
        #pragma unroll
        for (int j = 0; j < 4; ++j) {
            As[lc * 4 + j][lr] = av[j];
            Ws[lc * 4 + j][lr] = wv[j];
        }
        __syncthreads();
        #pragma unroll
        for (int k = 0; k < 16; ++k) {
            f4 a = *(const f4*)&As[k][tm * 4];
            f4 w = *(const f4*)&Ws[k][tn * 4];
            #pragma unroll
            for (int i = 0; i < 4; ++i)
                #pragma unroll
                for (int j = 0; j < 4; ++j)
                    acc[i][j] += a[i] * w[j];
        }
    }
    #pragma unroll
    for (int j = 0; j < 4; ++j) {
        const int n = n0 + tn * 4 + j;
        const float bias = bih[n] + bhh[n];
        #pragma unroll
        for (int i = 0; i < 4; ++i)
            store1<TO>(&out[(long)(m0 + tm * 4 + i) * NH + n], acc[i][j] + bias);
    }
}

// ===================== fused 3-layer recurrent kernel ==========================
__device__ __forceinline__ void poll64(const unsigned* fl, unsigned tgt, int lane)
{
    const unsigned long long* fp = (const unsigned long long*)fl + lane;
    for (;;) {
        unsigned long long v = __hip_atomic_load(fp, __ATOMIC_RELAXED,
                                                 __HIP_MEMORY_SCOPE_AGENT);
        unsigned lo = (unsigned)v, hi = (unsigned)(v >> 32);
        if (__all((int)(lo >= tgt && hi >= tgt))) break;
        __builtin_amdgcn_s_sleep(1);
    }
}

// 32 f16 (from LDS) dot 32 f32 (regs) -> fp32 acc; folds to v_fma_mix_f32.
__device__ __forceinline__ float mixrow(const ushort* hbase, const float* w, float acc)
{
    const uint4* hp = (const uint4*)hbase;
    uint4 c0 = hp[0], c1 = hp[1], c2 = hp[2], c3 = hp[3];
    unsigned uu[16] = { c0.x, c0.y, c0.z, c0.w, c1.x, c1.y, c1.z, c1.w,
                        c2.x, c2.y, c2.z, c2.w, c3.x, c3.y, c3.z, c3.w };
    #pragma unroll
    for (int j = 0; j < 16; ++j) {
        union { unsigned u; _Float16 h[2]; } t; t.u = uu[j];
        acc = fmaf((float)t.h[0], w[2 * j + 0], acc);
        acc = fmaf((float)t.h[1], w[2 * j + 1], acc);
    }
    return acc;
}

template <typename TP0>
__global__ __launch_bounds__(512)
void fused_kernel(const float* __restrict__ whh, const float* __restrict__ wih1,
                  const float* __restrict__ wih2, const float* __restrict__ bih,
                  const float* __restrict__ bhh, const TP0* __restrict__ P0,
                  ushort* __restrict__ Hr, unsigned* __restrict__ sy)
{
    __shared__ ushort hs0[16 * NH];      // 32 KB f16 h per layer (state of g-1)
    __shared__ ushort hs1[16 * NH];
    __shared__ ushort hs2[16 * NH];
    __shared__ float red[32][260];       // 33.3 KB tk-partials

    const int tid  = threadIdx.x;
    const int wg   = blockIdx.x;
    const int rank = wg & 63, set = wg >> 6, lane = tid & 63;
    const int nBase = rank << 4;
    const int tk = tid >> 4, tn = tid & 15;   // 32 k-chunks x 16 n-rows
    const int ko = tk << 5;                   // 32 k per thread

    // ---- 5 weight slices -> registers (f32, exact) ----
    float w0[32], wA[32], w1[32], wB[32], w2[32];
    {
        const long ro = (long)(nBase + tn) * NH + ko;
        #pragma unroll
        for (int j = 0; j < 8; ++j) {
            *(f4*)&w0[j * 4] = *(const f4*)&whh[ro + j * 4];
            *(f4*)&w1[j * 4] = *(const f4*)&whh[(long)NH * NH + ro + j * 4];
            *(f4*)&w2[j * 4] = *(const f4*)&whh[2L * NH * NH + ro + j * 4];
            *(f4*)&wA[j * 4] = *(const f4*)&wih1[ro + j * 4];
            *(f4*)&wB[j * 4] = *(const f4*)&wih2[ro + j * 4];
        }
    }
    // ---- reducer constants (tid<128: b=tid>>3, n-pair=tid&7) ----
    const int rb = tid >> 3, rp = tid & 7;
    const int n2 = nBase + rp * 2;
    float bs10 = 0, bs11 = 0, bs20 = 0, bs21 = 0;
    if (tid < 128) {
        bs10 = bih[NH + n2] + bhh[NH + n2];
        bs11 = bih[NH + n2 + 1] + bhh[NH + n2 + 1];
        bs20 = bih[2 * NH + n2] + bhh[2 * NH + n2];
        bs21 = bih[2 * NH + n2 + 1] + bhh[2 * NH + n2 + 1];
    }
    for (int i = tid; i < 16 * NH / 2; i += 512) {   // h[-1] = 0 all layers
        ((unsigned*)hs0)[i] = 0; ((unsigned*)hs1)[i] = 0; ((unsigned*)hs2)[i] = 0;
    }
    __syncthreads();

    unsigned* fl0 = sy + (set * 3 + 0) * 128;
    unsigned* fl1 = sy + (set * 3 + 1) * 128;
    unsigned* fl2 = sy + (set * 3 + 2) * 128;
    ushort* H0 = Hr;                 // [layer][slot][64*1024] f16
    ushort* H1 = Hr + 2 * 65536;
    ushort* H2 = Hr + 4 * 65536;
    const int sOff = set * 16384 + tid * 32;        // stage src offset (u16)
    const long pBase = ((long)set * 16 + rb) * NT;  // P0 row base (reducers)
    const int oIdx = rb * 16 + rp * 2;              // red column pair

    #pragma unroll 1
    for (int g = 0; g < NSTEP; ++g) {
        const int slot = g & 1, oslot = slot ^ 1;
        const bool a0 = (g <= NT - 1);
        const bool a1 = (g >= 1) && (g <= NT);
        const bool a2 = (g >= 2) && (g <= NT + 1);
        const bool sg1 = (g >= 2) && (g <= NT + 1);   // stage h1 during P0
        const bool sg2 = (g >= 3) && (g <= NT + 1);   // stage h2 during P1
        const bool sg0 = (g <= NT - 1);               // stage h0 during P2
        float acc[16];
        f4 st[4];

        // ================= PHASE 0 : layer 0 (ts = g) =================
        float p00 = 0.f, p01 = 0.f;
        if (a0 && tid < 128) {
            const long pa = (pBase + g) * NH + n2;
            p00 = load1<TP0>(&P0[pa]); p01 = load1<TP0>(&P0[pa + 1]);
        }
        if (a0) {
            #pragma unroll
            for (int b = 0; b < 16; ++b)
                acc[b] = mixrow(&hs0[b * NH + ko], w0, 0.f);
        }
        if (sg1) {   // stage h1 (published P1(g-1), flag g) -> hide under reduce
            poll64(fl1, (unsigned)g, lane);
            const char* sp = (const char*)(H1 + oslot * 65536 + sOff);
            #pragma unroll
            for (int q = 0; q < 4; ++q)
                asm volatile("global_load_dwordx4 %0, %1, off sc0 sc1"
                             : "=v"(st[q]) : "v"(sp + q * 16) : "memory");
        }
        if (a0) {
            #pragma unroll
            for (int b = 0; b < 16; ++b) red[tk][b * 16 + tn] = acc[b];
        }
        __syncthreads();
        if (a0 && tid < 128) {
            float s0 = 0.f, s1 = 0.f;
            #pragma unroll
            for (int q = 0; q < 32; ++q) { s0 += red[q][oIdx]; s1 += red[q][oIdx + 1]; }
            const float v0 = fmaxf(s0 + p00, 0.f), v1 = fmaxf(s1 + p01, 0.f);
            __hip_atomic_store((unsigned*)(H0 + slot * 65536 + ((set * 16 + rb) << 10) + n2),
                               packh(v0, v1), __ATOMIC_RELAXED, __HIP_MEMORY_SCOPE_AGENT);
            asm volatile("s_waitcnt vmcnt(0)" ::: "memory");
            if (lane == 0)
                __hip_atomic_store(&fl0[rank * 2 + (tid >> 6)], (unsigned)(g + 1),
                                   __ATOMIC_RELAXED, __HIP_MEMORY_SCOPE_AGENT);
        }
        if (sg1) {
            asm volatile("s_waitcnt vmcnt(0)" ::: "memory");
            char* dp = (char*)hs1 + tid * 64;
            #pragma unroll
            for (int q = 0; q < 4; ++q) *(f4*)(dp + q * 16) = st[q];
        }
        __syncthreads();

        // ================= PHASE 1 : layer 1 (ts = g-1) =================
        if (a1) {
            #pragma unroll
            for (int b = 0; b < 16; ++b) {
                float a = mixrow(&hs0[b * NH + ko], wA, 0.f);     // W_ih1 @ h0
                acc[b] = mixrow(&hs1[b * NH + ko], w1, a);        // + W_hh1 @ h1
            }
        }
        if (sg2) {   // stage h2 (published P2(g-1), flag g)
            poll64(fl2, (unsigned)g, lane);
            const char* sp = (const char*)(H2 + oslot * 65536 + sOff);
            #pragma unroll
            for (int q = 0; q < 4; ++q)
                asm volatile("global_load_dwordx4 %0, %1, off sc0 sc1"
                             : "=v"(st[q]) : "v"(sp + q * 16) : "memory");
        }
        if (a1) {
            #pragma unroll
            for (int b = 0; b < 16; ++b) red[tk][b * 16 + tn] = acc[b];
        }
        __syncthreads();
        if (a1 && tid < 128) {
            float s0 = 0.f, s1 = 0.f;
            #pragma unroll
            for (int q = 0; q < 32; ++q) { s0 += red[q][oIdx]; s1 += red[q][oIdx + 1]; }
            const float v0 = fmaxf(s0 + bs10, 0.f), v1 = fmaxf(s1 + bs11, 0.f);
            __hip_atomic_store((unsigned*)(H1 + slot * 65536 + ((set * 16 + rb) << 10) + n2),
                               packh(v0, v1), __ATOMIC_RELAXED, __HIP_MEMORY_SCOPE_AGENT);
            asm volatile("s_waitcnt vmcnt(0)" ::: "memory");
            if (lane == 0)
                __hip_atomic_store(&fl1[rank * 2 + (tid >> 6)], (unsigned)(g + 1),
                                   __ATOMIC_RELAXED, __HIP_MEMORY_SCOPE_AGENT);
        }
        if (sg2) {
            asm volatile("s_waitcnt vmcnt(0)" ::: "memory");
            char* dp = (char*)hs2 + tid * 64;
            #pragma unroll
            for (int q = 0; q < 4; ++q) *(f4*)(dp + q * 16) = st[q];
        }
        __syncthreads();

        // ================= PHASE 2 : layer 2 (ts = g-2) =================
        if (a2) {
            #pragma unroll
            for (int b = 0; b < 16; ++b) {
                float a = mixrow(&hs1[b * NH + ko], wB, 0.f);     // W_ih2 @ h1
                acc[b] = mixrow(&hs2[b * NH + ko], w2, a);        // + W_hh2 @ h2
            }
        }
        if (sg0) {   // stage h0 (published P0(g), flag g+1)
            poll64(fl0, (unsigned)(g + 1), lane);
            const char* sp = (const char*)(H0 + slot * 65536 + sOff);
            #pragma unroll
            for (int q = 0; q < 4; ++q)
                asm volatile("global_load_dwordx4 %0, %1, off sc0 sc1"
                             : "=v"(st[q]) : "v"(sp + q * 16) : "memory");
        }
        if (a2) {
            #pragma unroll
            for (int b = 0; b < 16; ++b) red[tk][b * 16 + tn] = acc[b];
        }
        __syncthreads();
        if (a2 && tid < 128) {
            float s0 = 0.f, s1 = 0.f;
            #pragma unroll
            for (int q = 0; q < 32; ++q) { s0 += red[q][oIdx]; s1 += red[q][oIdx + 1]; }
            const float v0 = fmaxf(s0 + bs20, 0.f), v1 = fmaxf(s1 + bs21, 0.f);
            __hip_atomic_store((unsigned*)(H2 + slot * 65536 + ((set * 16 + rb) << 10) + n2),
                               packh(v0, v1), __ATOMIC_RELAXED, __HIP_MEMORY_SCOPE_AGENT);
            asm volatile("s_waitcnt vmcnt(0)" ::: "memory");
            if (lane == 0)
                __hip_atomic_store(&fl2[rank * 2 + (tid >> 6)], (unsigned)(g + 1),
                                   __ATOMIC_RELAXED, __HIP_MEMORY_SCOPE_AGENT);
        }
        if (sg0) {
            asm volatile("s_waitcnt vmcnt(0)" ::: "memory");
            char* dp = (char*)hs0 + tid * 64;
            #pragma unroll
            for (int q = 0; q < 4; ++q) *(f4*)(dp + q * 16) = st[q];
        }
        __syncthreads();
    }
}

// ===================== final FC on h2[T-1] (f16 input) =====================
__global__ __launch_bounds__(128)
void fc16_kernel(const ushort* __restrict__ h2, const float* __restrict__ fcw,
                 const float* __restrict__ fcb, float* __restrict__ out)
{
    __shared__ float hrow[NH];
    const int b = blockIdx.x, tid = threadIdx.x;
    const ushort* src = h2 + (b << 10);
    #pragma unroll
    for (int j = 0; j < 2; ++j) {
        ushort4 u = *(const ushort4*)&src[tid * 8 + j * 4];
        hrow[tid * 8 + j * 4 + 0] = h2f(u.x);
        hrow[tid * 8 + j * 4 + 1] = h2f(u.y);
        hrow[tid * 8 + j * 4 + 2] = h2f(u.z);
        hrow[tid * 8 + j * 4 + 3] = h2f(u.w);
    }
    __syncthreads();
    float s = 0.f;
    const float* wr = &fcw[tid * NH];
    for (int k = 0; k < NH; k += 4) {
        f4 w = *(const f4*)&wr[k];
        s += w[0] * hrow[k] + w[1] * hrow[k + 1] + w[2] * hrow[k + 2] + w[3] * hrow[k + 3];
    }
    out[b * DOUT + tid] = s + fcb[tid];
}

// ===================== launcher =====================
template <typename TP0>
static void run_fused(const float* x, const float* wih0, const float* wihr,
                      const float* whh, const float* bih, const float* bhh,
                      unsigned* sy, ushort* Hr, TP0* P0, hipStream_t stream)
{
    proj_kernel<DIN, float, TP0><<<8192, 256, 0, stream>>>(x, wih0, bih, bhh, P0);
    const float* wp = whh; const float* wi1 = wihr; const float* wi2 = wihr + NH * NH;
    const float* bi = bih; const float* bh = bhh;
    const TP0* Pp = P0; ushort* H = Hr; unsigned* s = sy;
    void* args[8] = { &wp, &wi1, &wi2, &bi, &bh, &Pp, &H, &s };
    hipLaunchCooperativeKernel((const void*)fused_kernel<TP0>, dim3(256), dim3(512),
                               args, 0, stream);
}

extern "C" void kernel_launch(void* const* d_in, const int* in_sizes, int n_in,
                              void* d_out, int out_size, void* d_ws, size_t ws_size,
                              hipStream_t stream)
{
    (void)in_sizes; (void)n_in; (void)out_size;
    const float* x    = (const float*)d_in[0];
    const float* wih0 = (const float*)d_in[1];
    const float* wihr = (const float*)d_in[2];   // [2][H][H]
    const float* whh  = (const float*)d_in[3];   // [3][H][H]
    const float* bih  = (const float*)d_in[4];
    const float* bhh  = (const float*)d_in[5];
    const float* fcw  = (const float*)d_in[6];
    const float* fcb  = (const float*)d_in[7];
    float* out = (float*)d_out;

    char* ws = (char*)d_ws;
    unsigned* sy = (unsigned*)ws;                 // 8 KB flags (4 sets x 3 layers x 128)
    ushort* Hr = (ushort*)(ws + 8192);            // 3 layers x 2 slots x 64x1024 f16 = 768 KB
    char* base = ws + (1 << 20);                  // P0 (layer-0 pre) at 1 MB

    const size_t pF32 = (size_t)NB * NT * NH * 4; // 128 MiB
    hipMemsetAsync(sy, 0, 8192, stream);
    if (ws_size >= (size_t)(1 << 20) + pF32) {
        run_fused<float>(x, wih0, wihr, whh, bih, bhh, sy, Hr, (float*)base, stream);
    } else {
        run_fused<bfr>(x, wih0, wihr, whh, bih, bhh, sy, Hr, (bfr*)base, stream);
    }
    // fc on h2[T-1]: Hring layer 2, slot (513 & 1) = 1
    fc16_kernel<<<dim3(NB), dim3(128), 0, stream>>>(Hr + 5 * 65536, fcw, fcb, out);
}